// Round 12
// baseline (114.352 us; speedup 1.0000x reference)
//
#include <hip/hip_runtime.h>
#include <hip/hip_bf16.h>

// CRF NLL via chunk-parallel linear-space scan, register-resident H, 2-way
// in-wave ILP + in-wave pair fusion.
//   q^T_t = q^T_0 (M D_1)...(M D_T);  chunk: H <- diag(e_t) M^T H (16 steps).
// mfma_f32_16x16x16_bf16: B-layout == C/D-layout -> next step's B operand is
// the current C packed f32->bf16 in place (verified R8-R10).
//
// R11 theory: across R6-R10 the chunk scan ran ~1500 cyc/step vs a ~350-cyc
// issue floor -- the MFMA->pack->MFMA serial chain is latency-exposed and
// measured residency never exceeded ~1 wave/SIMD (scheduler never delivered
// cross-wave hiding). Fix: each wave interleaves TWO independent 16-step
// chunks (two register sets) -- chain A's stalls are filled by chain B
// in-wave, no scheduler cooperation needed. At scan end the wave multiplies
// its pair in-registers (LDS one-shot transpose of H1 to A-layout + 27 MFMA)
// -> 16 matrices/batch, so the separate merge kernel disappears and the
// final kernel does 16 serial matvecs + gold.

namespace {
constexpr int kB = 128;
constexpr int kS = 512;
constexpr int kT = 36;
constexpr int kStart = 34;
constexpr int kEnd = 35;
constexpr int kL = 16;     // steps per chunk
constexpr int kG = 16;     // pairs per batch; wave g covers steps [32g, 32g+32)
constexpr int kEStr = 48;  // Etab row stride (floats)
constexpr int kTS = 52;    // LDS transpose row stride (halfwords)

typedef __bf16 bf16x4 __attribute__((ext_vector_type(4)));
typedef short short4v __attribute__((ext_vector_type(4)));
typedef float f32x4 __attribute__((ext_vector_type(4)));
typedef int int2v __attribute__((ext_vector_type(2)));

__device__ __forceinline__ float readlane_f(float v, int lane) {
    return __builtin_bit_cast(float, __builtin_amdgcn_readlane(__builtin_bit_cast(int, v), lane));
}

__device__ __forceinline__ float wave_sum(float v) {
#pragma unroll
    for (int off = 32; off; off >>= 1) v += __shfl_xor(v, off, 64);
    return v;
}

__device__ __forceinline__ int wave_sum_i(int v) {
#pragma unroll
    for (int off = 32; off; off >>= 1) v += __shfl_xor(v, off, 64);
    return v;
}

#define MF16(a, b, c) __builtin_amdgcn_mfma_f32_16x16x16bf16_1k((a), (b), (c), 0, 0, 0)

// 27-MFMA 36x36(x48) product: CP_rt_ct = sum_kc AP_rt_kc * BP_kc_ct
#define MM27(AP, BP, CP) \
    f32x4 CP##_00 = MF16(AP##_00, BP##_00, z), CP##_01 = MF16(AP##_00, BP##_01, z), CP##_02 = MF16(AP##_00, BP##_02, z); \
    f32x4 CP##_10 = MF16(AP##_10, BP##_00, z), CP##_11 = MF16(AP##_10, BP##_01, z), CP##_12 = MF16(AP##_10, BP##_02, z); \
    f32x4 CP##_20 = MF16(AP##_20, BP##_00, z), CP##_21 = MF16(AP##_20, BP##_01, z), CP##_22 = MF16(AP##_20, BP##_02, z); \
    CP##_00 = MF16(AP##_01, BP##_10, CP##_00); CP##_01 = MF16(AP##_01, BP##_11, CP##_01); CP##_02 = MF16(AP##_01, BP##_12, CP##_02); \
    CP##_10 = MF16(AP##_11, BP##_10, CP##_10); CP##_11 = MF16(AP##_11, BP##_11, CP##_11); CP##_12 = MF16(AP##_11, BP##_12, CP##_12); \
    CP##_20 = MF16(AP##_21, BP##_10, CP##_20); CP##_21 = MF16(AP##_21, BP##_11, CP##_21); CP##_22 = MF16(AP##_21, BP##_12, CP##_22); \
    CP##_00 = MF16(AP##_02, BP##_20, CP##_00); CP##_01 = MF16(AP##_02, BP##_21, CP##_01); CP##_02 = MF16(AP##_02, BP##_22, CP##_02); \
    CP##_10 = MF16(AP##_12, BP##_20, CP##_10); CP##_11 = MF16(AP##_12, BP##_21, CP##_11); CP##_12 = MF16(AP##_12, BP##_22, CP##_12); \
    CP##_20 = MF16(AP##_22, BP##_20, CP##_20); CP##_21 = MF16(AP##_22, BP##_21, CP##_21); CP##_22 = MF16(AP##_22, BP##_22, CP##_22);

#define PK(cv, sv) ({ const f32x4 t_ = (cv) * (sv); bf16x4 h_;                  \
        h_[0] = (__bf16)t_[0]; h_[1] = (__bf16)t_[1];                           \
        h_[2] = (__bf16)t_[2]; h_[3] = (__bf16)t_[3];                           \
        __builtin_bit_cast(short4v, h_); })

// ===================== kernel 1: chunk pairs (2-way ILP) =====================

__global__ __attribute__((amdgpu_flat_work_group_size(64, 64),
                          amdgpu_waves_per_eu(2, 4)))
void crf_pair_kernel(const float* __restrict__ feats,    // (B,S,T)
                     const float* __restrict__ trans,    // (T,T)
                     const int* __restrict__ mask,       // (B,S)
                     __bf16* __restrict__ Hp,            // (B,G,36,36) bf16 row-major
                     float* __restrict__ lsc) {          // (B,G)
    const int b = blockIdx.x;
    const int g = blockIdx.y;
    const int lane = threadIdx.x;
    const int ln = lane & 15;
    const int quad = lane >> 4;

    __shared__ __align__(16) float Etab[2 * kL * kEStr];   // exp(feats), 1.0 pad
    __shared__ __align__(16) unsigned short Tr[48 * kTS];  // one-shot transpose

    // ---- sequence length (contiguous-prefix mask) ----
    const int* mb = mask + b * kS;
    int len = 0;
#pragma unroll
    for (int k = 0; k < kS / 64; ++k) len += mb[k * 64 + lane];
    len = wave_sum_i(len);  // in [256, 512]

    __bf16* Hout = Hp + (size_t)(b * kG + g) * (kT * kT);
    const int p0 = 2 * g, p1 = 2 * g + 1;
    const int cs0 = (p0 == 0) ? 1 : p0 * kL;
    const int n0 = min((p0 + 1) * kL, len) - cs0;
    const int cs1 = p1 * kL;
    const int n1 = min((p1 + 1) * kL, len) - cs1;

    if (n0 <= 0) {  // whole pair masked (len contiguous => n1 <= 0 too)
        for (int idx = lane; idx < kT * kT; idx += 64)
            Hout[idx] = (__bf16)((idx / kT == idx % kT) ? 1.f : 0.f);
        if (lane == 0) lsc[b * kG + g] = 0.f;
        return;
    }

    // ---- stage exp(feats) for both chunks (batched loads; all in-bounds:
    //      cs0+15 <= 495, cs1+15 <= 511) ----
    const float* fb = feats + (size_t)b * kS * kT;
    {
        float st[2 * kL];
#pragma unroll
        for (int it = 0; it < kL; ++it)
            st[it] = (lane < kT) ? fb[(size_t)(cs0 + it) * kT + lane] : 0.f;
#pragma unroll
        for (int it = 0; it < kL; ++it)
            st[kL + it] = (lane < kT) ? fb[(size_t)(cs1 + it) * kT + lane] : 0.f;
#pragma unroll
        for (int it = 0; it < 2 * kL; ++it)
            if (lane < kEStr)
                Etab[it * kEStr + lane] = (lane < kT) ? __expf(st[it]) : 1.0f;
    }
    __builtin_amdgcn_s_waitcnt(0);  // single wave: own LDS writes visible

    // ---- A = M^T bf16 frags (fixed): A(rt,kc)[m][k] = exp(trans[k][m]) ----
    auto afrag = [&](int rt, int kc) {
        bf16x4 r;
        const int m = rt * 16 + ln;
#pragma unroll
        for (int e = 0; e < 4; ++e) {
            const int k = kc * 16 + quad * 4 + e;
            float v = 0.f;
            if (m < kT && k < kT) v = __expf(trans[k * kT + m]);
            r[e] = (__bf16)v;
        }
        return __builtin_bit_cast(short4v, r);
    };
    const short4v a_00 = afrag(0, 0), a_01 = afrag(0, 1), a_02 = afrag(0, 2);
    const short4v a_10 = afrag(1, 0), a_11 = afrag(1, 1), a_12 = afrag(1, 2);
    const short4v a_20 = afrag(2, 0), a_21 = afrag(2, 1), a_22 = afrag(2, 2);

    // ---- B = H (both chunks), register-resident; init H = I ----
    auto binit = [&](int kc, int ct) {
        bf16x4 r;
        const int n = ct * 16 + ln;
#pragma unroll
        for (int e = 0; e < 4; ++e) {
            const int k = kc * 16 + quad * 4 + e;
            r[e] = (__bf16)((k == n && k < kT) ? 1.f : 0.f);
        }
        return __builtin_bit_cast(short4v, r);
    };
    short4v b0_00 = binit(0, 0), b0_01 = binit(0, 1), b0_02 = binit(0, 2);
    short4v b0_10 = binit(1, 0), b0_11 = binit(1, 1), b0_12 = binit(1, 2);
    short4v b0_20 = binit(2, 0), b0_21 = binit(2, 1), b0_22 = binit(2, 2);
    short4v b1_00 = binit(0, 0), b1_01 = binit(0, 1), b1_02 = binit(0, 2);
    short4v b1_10 = binit(1, 0), b1_11 = binit(1, 1), b1_12 = binit(1, 2);
    short4v b1_20 = binit(2, 0), b1_21 = binit(2, 1), b1_22 = binit(2, 2);

    // ---- interleaved scan: two independent chains per wave ----
    float logC = 0.f;
    const f32x4 z = {0.f, 0.f, 0.f, 0.f};
    const int nmax = max(n0, n1);
    for (int tl = 0; tl < nmax; ++tl) {
        // stale renorm sources (VALU-written regs, no MFMA hazard)
        const int w11_0 = __builtin_amdgcn_readlane(__builtin_bit_cast(int2v, b0_00).x, 1);
        const int w11_1 = __builtin_amdgcn_readlane(__builtin_bit_cast(int2v, b1_00).x, 1);
        // row scales e[m], m = rt*16 + quad*4 + reg
        const float* et0 = &Etab[tl * kEStr + quad * 4];
        const f32x4 e0a = *(const f32x4*)(et0 + 0);
        const f32x4 e0b = *(const f32x4*)(et0 + 16);
        const f32x4 e0c = *(const f32x4*)(et0 + 32);
        const float* et1 = &Etab[(kL + tl) * kEStr + quad * 4];
        const f32x4 e1a = *(const f32x4*)(et1 + 0);
        const f32x4 e1b = *(const f32x4*)(et1 + 16);
        const f32x4 e1c = *(const f32x4*)(et1 + 32);

        MM27(a, b0, c0)   // chain A
        MM27(a, b1, c1)   // chain B (independent -> fills A's stalls)

        float rs0 = 1.f, rs1 = 1.f;
        if ((tl & 3) == 3) {  // renorm every 4 steps (uniform positive scale)
            if (tl < n0) {
                const float s = __builtin_bit_cast(float, (unsigned)w11_0 & 0xFFFF0000u);
                rs0 = __builtin_amdgcn_rcpf(s);
                logC += __logf(s);
            }
            if (tl < n1) {
                const float s = __builtin_bit_cast(float, (unsigned)w11_1 & 0xFFFF0000u);
                rs1 = __builtin_amdgcn_rcpf(s);
                logC += __logf(s);
            }
        }
        const f32x4 s0a = e0a * rs0, s0b = e0b * rs0, s0c = e0c * rs0;
        const f32x4 s1a = e1a * rs1, s1b = e1b * rs1, s1c = e1c * rs1;

        if (tl < n0) {  // uniform predicate: masked steps keep H
            b0_00 = PK(c0_00, s0a); b0_01 = PK(c0_01, s0a); b0_02 = PK(c0_02, s0a);
            b0_10 = PK(c0_10, s0b); b0_11 = PK(c0_11, s0b); b0_12 = PK(c0_12, s0b);
            b0_20 = PK(c0_20, s0c); b0_21 = PK(c0_21, s0c); b0_22 = PK(c0_22, s0c);
        }
        if (tl < n1) {
            b1_00 = PK(c1_00, s1a); b1_01 = PK(c1_01, s1a); b1_02 = PK(c1_02, s1a);
            b1_10 = PK(c1_10, s1b); b1_11 = PK(c1_11, s1b); b1_12 = PK(c1_12, s1b);
            b1_20 = PK(c1_20, s1c); b1_21 = PK(c1_21, s1c); b1_22 = PK(c1_22, s1c);
        }
    }

    // ---- pair fusion: Hpair = H1 * H0 (apply chunk0 first) ----
    // H1 is in B-layout (lane=n, regs=k); its A-layout needs lane=m, regs=k:
    // one-shot LDS transpose Tr[n][k] then contiguous b64 reads.
#define TW(Bv, kc, ct) *(short4v*)&Tr[((ct)*16 + ln) * kTS + (kc)*16 + quad * 4] = Bv;
    TW(b1_00, 0, 0) TW(b1_01, 0, 1) TW(b1_02, 0, 2)
    TW(b1_10, 1, 0) TW(b1_11, 1, 1) TW(b1_12, 1, 2)
    TW(b1_20, 2, 0) TW(b1_21, 2, 1) TW(b1_22, 2, 2)
#undef TW
    __builtin_amdgcn_s_waitcnt(0);
#define TR(rt, kc) (*(const short4v*)&Tr[((rt)*16 + ln) * kTS + (kc)*16 + quad * 4])
    const short4v pa_00 = TR(0, 0), pa_01 = TR(0, 1), pa_02 = TR(0, 2);
    const short4v pa_10 = TR(1, 0), pa_11 = TR(1, 1), pa_12 = TR(1, 2);
    const short4v pa_20 = TR(2, 0), pa_21 = TR(2, 1), pa_22 = TR(2, 2);
#undef TR

    MM27(pa, b0, cp)  // cp = H1 * H0

    // renorm result by its [1,1] (uniform, positive), store row-major bf16
    const float sP = readlane_f(cp_00[1], 1);
    const float rsP = __builtin_amdgcn_rcpf(sP);
    logC += __logf(sP);
    const f32x4 rv = {rsP, rsP, rsP, rsP};
#define STOREC(cv, rt, ct) {                                                    \
    const bf16x4 h_ = __builtin_bit_cast(bf16x4, PK(cv, rv));                   \
    const int n_ = (ct)*16 + ln;                                                \
    _Pragma("unroll") for (int e = 0; e < 4; ++e) {                             \
        const int m_ = (rt)*16 + quad * 4 + e;                                  \
        if (m_ < kT && n_ < kT) Hout[m_ * kT + n_] = h_[e]; } }
    STOREC(cp_00, 0, 0) STOREC(cp_01, 0, 1) STOREC(cp_02, 0, 2)
    STOREC(cp_10, 1, 0) STOREC(cp_11, 1, 1) STOREC(cp_12, 1, 2)
    STOREC(cp_20, 2, 0) STOREC(cp_21, 2, 1) STOREC(cp_22, 2, 2)
#undef STOREC
    if (lane == 0) lsc[b * kG + g] = logC;
}

// ============================ kernel 2: final ============================

// term n of the 36-dot: accumulator a (0..3), h-vector g (= n/4), component c (= n%4)
#define FORK36(X) \
    X(0,0,0,0) X(1,1,0,1) X(2,2,0,2) X(3,3,0,3) \
    X(4,0,1,0) X(5,1,1,1) X(6,2,1,2) X(7,3,1,3) \
    X(8,0,2,0) X(9,1,2,1) X(10,2,2,2) X(11,3,2,3) \
    X(12,0,3,0) X(13,1,3,1) X(14,2,3,2) X(15,3,3,3) \
    X(16,0,4,0) X(17,1,4,1) X(18,2,4,2) X(19,3,4,3) \
    X(20,0,5,0) X(21,1,5,1) X(22,2,5,2) X(23,3,5,3) \
    X(24,0,6,0) X(25,1,6,1) X(26,2,6,2) X(27,3,6,3) \
    X(28,0,7,0) X(29,1,7,1) X(30,2,7,2) X(31,3,7,3) \
    X(32,0,8,0) X(33,1,8,1) X(34,2,8,2) X(35,3,8,3)

__global__ __attribute__((amdgpu_flat_work_group_size(64, 64),
                          amdgpu_waves_per_eu(1, 1)))
void crf_final_kernel(const float* __restrict__ feats,
                      const float* __restrict__ trans,
                      const int* __restrict__ mask,
                      const int* __restrict__ tags,
                      const __bf16* __restrict__ Hp,
                      const float* __restrict__ lsc,
                      float* __restrict__ out) {
    const int b = blockIdx.x;
    const int j = threadIdx.x;
    const float* fbase = feats + (size_t)b * kS * kT;
    const int* mb = mask + b * kS;
    const int* tb = tags + b * kS;

    int len = 0;
#pragma unroll
    for (int k = 0; k < kS / 64; ++k) len += mb[k * 64 + j];
    len = wave_sum_i(len);

    const float ME = (j < kT) ? __expf(trans[j * kT + kEnd]) : 0.f;

    // init: alpha0 = feats[b,0,:] + trans[START,:]
    float a0 = -1e30f;
    if (j < kT) a0 = fbase[j] + trans[kStart * kT + j];
    float C = readlane_f(a0, 0);
    float q = __expf(a0 - C);  // lanes >= 36 -> 0

    const int jr = (j < kT) ? j : 0;
    for (int g = 0; g < kG; ++g) {
        const __bf16* rp = Hp + ((size_t)(b * kG + g) * kT + jr) * kT;
        const bf16x4 h0 = *(const bf16x4*)(rp + 0);
        const bf16x4 h1 = *(const bf16x4*)(rp + 4);
        const bf16x4 h2 = *(const bf16x4*)(rp + 8);
        const bf16x4 h3 = *(const bf16x4*)(rp + 12);
        const bf16x4 h4 = *(const bf16x4*)(rp + 16);
        const bf16x4 h5 = *(const bf16x4*)(rp + 20);
        const bf16x4 h6 = *(const bf16x4*)(rp + 24);
        const bf16x4 h7 = *(const bf16x4*)(rp + 28);
        const bf16x4 h8 = *(const bf16x4*)(rp + 32);
#define BRD2(n, a, g2, c) const float bb##n = readlane_f(q, n);
        FORK36(BRD2)
#undef BRD2
        float v0 = 0.f, v1 = 0.f, v2 = 0.f, v3 = 0.f;
#define FMA2(n, a, g2, c) v##a = fmaf(bb##n, (float)h##g2[c], v##a);
        FORK36(FMA2)
#undef FMA2
        const float qn = (v0 + v1) + (v2 + v3);
        q = (j < kT) ? qn : 0.f;
        C += lsc[b * kG + g];
        const float s = readlane_f(q, 0);  // positive (state-0 alpha)
        q *= __builtin_amdgcn_rcpf(s);
        C += __logf(s);
    }

    // forward score
    const float ssum = wave_sum(q * ME);
    const float forward_b = C + __logf(ssum);

    // gold score
    float g2 = 0.f;
    for (int k = j; k < kS; k += 64) {
        if (k < len) {
            const int tg = tb[k];
            const int pv = (k == 0) ? kStart : tb[k - 1];
            g2 += fbase[(size_t)k * kT + tg] + trans[pv * kT + tg];
        }
    }
    g2 = wave_sum(g2);

    if (j == 0) {
        g2 += trans[tb[len - 1] * kT + kEnd];
        atomicAdd(out, (forward_b - g2) * (1.0f / kB));
    }
}

}  // namespace

extern "C" void kernel_launch(void* const* d_in, const int* in_sizes, int n_in,
                              void* d_out, int out_size, void* d_ws, size_t ws_size,
                              hipStream_t stream) {
    const float* feats = (const float*)d_in[0];
    const float* trans = (const float*)d_in[1];
    const int* mask = (const int*)d_in[2];
    const int* tags = (const int*)d_in[3];
    float* out = (float*)d_out;

    __bf16* Hp = (__bf16*)d_ws;                              // B*G*1296 bf16 = 5.3 MB
    float* lsc = (float*)(Hp + (size_t)kB * kG * kT * kT);   // B*G f32

    (void)hipMemsetAsync(out, 0, sizeof(float), stream);
    crf_pair_kernel<<<dim3(kB, kG), dim3(64), 0, stream>>>(feats, trans, mask, Hp, lsc);
    crf_final_kernel<<<dim3(kB), dim3(64), 0, stream>>>(feats, trans, mask, tags,
                                                        Hp, lsc, out);
}